// Round 3
// baseline (418.276 us; speedup 1.0000x reference)
//
#include <hip/hip_runtime.h>
#include <hip/hip_bf16.h>

// Problem: B=2, L=2048, NH=8, DH=64, DM=512, TEMP=8.
// Outputs (concat fp32): qh (2,8,2048,64) then attn (2,8,2048,2048).
//
// Pipeline: convert(f32->bf16) -> proj GEMM (qh,kh) -> attn row-sums -> attn write.
// attn write is the only HBM-heavy dispatch (268 MB fp32) ~ 43 us floor.

typedef __attribute__((ext_vector_type(8))) short bf16x8_t;   // MFMA A/B frag
typedef __attribute__((ext_vector_type(4))) float f32x4_t;    // MFMA C/D frag
typedef __attribute__((ext_vector_type(4))) short s16x4_t;

#define MFMA16(a, b, c) __builtin_amdgcn_mfma_f32_16x16x32_bf16((a), (b), (c), 0, 0, 0)

// exp(x/8) == exp2(x * 0.125*log2(e))
#define EXP2_SCALE 0.18033688f

__device__ __forceinline__ short f2bf(float x) {
    union { float f; unsigned u; } v; v.f = x;
    unsigned r = v.u + 0x7fffu + ((v.u >> 16) & 1u);
    return (short)(r >> 16);
}
__device__ __forceinline__ float bf2f(short x) {
    union { float f; unsigned u; } v;
    v.u = ((unsigned)(unsigned short)x) << 16;
    return v.f;
}

// ---------------------------------------------------------------------------
// Kernel 0: f32 -> bf16 convert of q, k, Wq, Wk (4 segments, float4 granular)
// ---------------------------------------------------------------------------
__global__ __launch_bounds__(256) void convert_kernel(
    const float* __restrict__ s0, short* __restrict__ d0, int n0,   // q  (vec4 count)
    const float* __restrict__ s1, short* __restrict__ d1, int n1,   // k
    const float* __restrict__ s2, short* __restrict__ d2, int n2,   // Wq
    const float* __restrict__ s3, short* __restrict__ d3, int n3)   // Wk
{
    int i = blockIdx.x * 256 + threadIdx.x;
    const float* s; short* d; int j = i;
    if (j < n0)               { s = s0; d = d0; }
    else if ((j -= n0) < n1)  { s = s1; d = d1; }
    else if ((j -= n1) < n2)  { s = s2; d = d2; }
    else if ((j -= n2) < n3)  { s = s3; d = d3; }
    else return;
    f32x4_t v = *(const f32x4_t*)(s + (size_t)j * 4);
    s16x4_t o;
    o[0] = f2bf(v[0]); o[1] = f2bf(v[1]); o[2] = f2bf(v[2]); o[3] = f2bf(v[3]);
    *(s16x4_t*)(d + (size_t)j * 4) = o;
}

// ---------------------------------------------------------------------------
// Kernel 1: C = A @ W^T, A (4096x512 bf16), W (512x512 bf16). grid (32,4,2).
// ---------------------------------------------------------------------------
__global__ __launch_bounds__(256) void proj_kernel(
    const short* __restrict__ q, const short* __restrict__ k,
    const short* __restrict__ Wq, const short* __restrict__ Wk,
    float* __restrict__ qh_f32, short* __restrict__ qh_bf,
    short* __restrict__ kh_bf)
{
    const int z  = blockIdx.z;
    const short* A = z ? k  : q;
    const short* W = z ? Wk : Wq;
    const int m0 = blockIdx.x * 128;
    const int n0 = blockIdx.y * 128;
    const int tid  = threadIdx.x;
    const int wave = tid >> 6;
    const int lane = tid & 63;
    const int wm = (wave >> 1) * 64;
    const int wn = (wave & 1) * 64;
    const int lrow = lane & 15;
    const int lk   = (lane >> 4) * 8;

    f32x4_t acc[4][4] = {};

    for (int ks = 0; ks < 512; ks += 32) {
        bf16x8_t af[4], bfr[4];
#pragma unroll
        for (int mt = 0; mt < 4; ++mt)
            af[mt] = *(const bf16x8_t*)(A + (size_t)(m0 + wm + mt * 16 + lrow) * 512 + ks + lk);
#pragma unroll
        for (int nt = 0; nt < 4; ++nt)
            bfr[nt] = *(const bf16x8_t*)(W + (size_t)(n0 + wn + nt * 16 + lrow) * 512 + ks + lk);
#pragma unroll
        for (int mt = 0; mt < 4; ++mt)
#pragma unroll
            for (int nt = 0; nt < 4; ++nt)
                acc[mt][nt] = MFMA16(af[mt], bfr[nt], acc[mt][nt]);
    }

    const int g4 = (lane >> 4) * 4;
#pragma unroll
    for (int mt = 0; mt < 4; ++mt) {
#pragma unroll
        for (int r = 0; r < 4; ++r) {
            const int m  = m0 + wm + mt * 16 + g4 + r;
            const int bb = m >> 11;
            const int l  = m & 2047;
#pragma unroll
            for (int nt = 0; nt < 4; ++nt) {
                const int n = n0 + wn + nt * 16 + lrow;
                const int h = n >> 6;
                const int d = n & 63;
                const size_t idx = ((size_t)(bb * 8 + h) * 2048 + l) * 64 + d;
                const float v = acc[mt][nt][r];
                if (z == 0) {
                    qh_f32[idx] = v;
                    qh_bf[idx]  = f2bf(v);
                } else {
                    kh_bf[idx]  = f2bf(v);
                }
            }
        }
    }
}

// ---------------------------------------------------------------------------
// Kernel 2: per-row softmax denominators -> rinv (16 x 2048 fp32 in ws).
// grid (16,128): x=b*8+h, y=16-row q tile. 4 waves x 512-key slices. Tiny LDS.
// ---------------------------------------------------------------------------
__global__ __launch_bounds__(256) void attn_sums_kernel(
    const short* __restrict__ qh, const short* __restrict__ kh,
    const int* __restrict__ mask, float* __restrict__ rinv)
{
    const int bh = blockIdx.x;
    const int b  = bh >> 3;
    const int q0 = blockIdx.y * 16;
    const int tid = threadIdx.x;
    const int wave = tid >> 6;
    const int lane = tid & 63;
    const int lrow = lane & 15;
    const int lk   = (lane >> 4) * 8;
    const int g4   = (lane >> 4) * 4;

    __shared__ float psum[4 * 16];

    const short* Qb = qh + (size_t)bh * 2048 * 64;
    const short* Kb = kh + (size_t)bh * 2048 * 64;
    const int*   Mb = mask + b * 2048;

    const int qrow = q0 + lrow;
    const bf16x8_t qf0 = *(const bf16x8_t*)(Qb + (size_t)qrow * 64 + lk);
    const bf16x8_t qf1 = *(const bf16x8_t*)(Qb + (size_t)qrow * 64 + lk + 32);

    float sum[4] = {0.f, 0.f, 0.f, 0.f};
    const int k0 = wave * 512;
#pragma unroll 4
    for (int kc = k0; kc < k0 + 512; kc += 16) {
        const short* kp = Kb + (size_t)(kc + lrow) * 64 + lk;
        const bf16x8_t b0 = *(const bf16x8_t*)kp;
        const bf16x8_t b1 = *(const bf16x8_t*)(kp + 32);
        const float bias2 = Mb[kc + lrow] ? 0.f : -1e9f;
        f32x4_t acc = {};
        acc = MFMA16(qf0, b0, acc);
        acc = MFMA16(qf1, b1, acc);
#pragma unroll
        for (int r = 0; r < 4; ++r)
            sum[r] += __builtin_amdgcn_exp2f(acc[r] * EXP2_SCALE + bias2);
    }
#pragma unroll
    for (int m = 1; m < 16; m <<= 1)
#pragma unroll
        for (int r = 0; r < 4; ++r)
            sum[r] += __shfl_xor(sum[r], m, 64);
    if (lrow == 0) {
#pragma unroll
        for (int r = 0; r < 4; ++r)
            psum[wave * 16 + g4 + r] = sum[r];
    }
    __syncthreads();
    if (tid < 16)
        rinv[bh * 2048 + q0 + tid] =
            1.f / (psum[tid] + psum[16 + tid] + psum[32 + tid] + psum[48 + tid]);
}

// ---------------------------------------------------------------------------
// Kernel 3: recompute scores, normalize, write attn with coalesced 1KB bursts.
// grid (16,128). Per-wave private 16x264-short stage tile (no __syncthreads);
// LDS 33.8 KB -> 4 blocks/CU. Flushes every 256 keys.
// ---------------------------------------------------------------------------
__global__ __launch_bounds__(256) void attn_write_kernel(
    const short* __restrict__ qh, const short* __restrict__ kh,
    const int* __restrict__ mask, const float* __restrict__ rinv,
    float* __restrict__ attn)
{
    const int bh = blockIdx.x;
    const int b  = bh >> 3;
    const int q0 = blockIdx.y * 16;
    const int tid = threadIdx.x;
    const int wave = tid >> 6;
    const int lane = tid & 63;
    const int lrow = lane & 15;
    const int lk   = (lane >> 4) * 8;
    const int g4   = (lane >> 4) * 4;

    __shared__ short stage[4 * 16 * 264];   // per-wave 16x264 (stride-padded)
    short* st = stage + wave * 16 * 264;

    const short* Qb = qh + (size_t)bh * 2048 * 64;
    const short* Kb = kh + (size_t)bh * 2048 * 64;
    const int*   Mb = mask + b * 2048;

    const int qrow = q0 + lrow;
    const bf16x8_t qf0 = *(const bf16x8_t*)(Qb + (size_t)qrow * 64 + lk);
    const bf16x8_t qf1 = *(const bf16x8_t*)(Qb + (size_t)qrow * 64 + lk + 32);

    float rv[4];
#pragma unroll
    for (int r = 0; r < 4; ++r)
        rv[r] = rinv[bh * 2048 + q0 + g4 + r];

    float* outb = attn + ((size_t)bh * 2048 + q0) * 2048;

#pragma unroll
    for (int t = 0; t < 2; ++t) {
        const int kbase = wave * 512 + t * 256;
        // score + normalize + stage (bf16)
#pragma unroll 4
        for (int kl = 0; kl < 256; kl += 16) {
            const int kc = kbase + kl;
            const short* kp = Kb + (size_t)(kc + lrow) * 64 + lk;
            const bf16x8_t b0 = *(const bf16x8_t*)kp;
            const bf16x8_t b1 = *(const bf16x8_t*)(kp + 32);
            const float bias2 = Mb[kc + lrow] ? 0.f : -1e9f;
            f32x4_t acc = {};
            acc = MFMA16(qf0, b0, acc);
            acc = MFMA16(qf1, b1, acc);
#pragma unroll
            for (int r = 0; r < 4; ++r) {
                const float e = __builtin_amdgcn_exp2f(acc[r] * EXP2_SCALE + bias2) * rv[r];
                st[(g4 + r) * 264 + kl + lrow] = f2bf(e);
            }
        }
        // flush: one 1KB store per row (64 lanes x 16B, fully coalesced).
        // Same-wave producer/consumer: compiler's lgkmcnt waits suffice.
#pragma unroll
        for (int row = 0; row < 16; ++row) {
            const s16x4_t v = *(const s16x4_t*)(st + row * 264 + lane * 4);
            f32x4_t o;
            o[0] = bf2f(v[0]); o[1] = bf2f(v[1]);
            o[2] = bf2f(v[2]); o[3] = bf2f(v[3]);
            *(f32x4_t*)(outb + (size_t)row * 2048 + kbase + lane * 4) = o;
        }
    }
}

// ---------------------------------------------------------------------------
extern "C" void kernel_launch(void* const* d_in, const int* in_sizes, int n_in,
                              void* d_out, int out_size, void* d_ws, size_t ws_size,
                              hipStream_t stream)
{
    const float* q    = (const float*)d_in[0];
    const float* k    = (const float*)d_in[1];
    const int*   mask = (const int*)  d_in[3];
    const float* Wq   = (const float*)d_in[4];
    const float* Wk   = (const float*)d_in[5];

    float* out    = (float*)d_out;
    float* qh_f32 = out;                 // 2,097,152 floats
    float* attn   = out + 2097152;       // 67,108,864 floats

    // ws layout (shorts): q_bf, k_bf, Wq_bf, Wk_bf, qh_bf, kh_bf; then rinv f32
    short* q_bf  = (short*)d_ws;
    short* k_bf  = q_bf  + 2097152;
    short* Wq_bf = k_bf  + 2097152;
    short* Wk_bf = Wq_bf + 262144;
    short* qh_bf = Wk_bf + 262144;
    short* kh_bf = qh_bf + 2097152;
    float* rinv  = (float*)(kh_bf + 2097152);   // 32768 floats

    // vec4 counts: q 524288, k 524288, Wq 65536, Wk 65536 -> total 1179648
    convert_kernel<<<dim3(1179648 / 256), 256, 0, stream>>>(
        q, q_bf, 524288, k, k_bf, 524288, Wq, Wq_bf, 65536, Wk, Wk_bf, 65536);

    proj_kernel<<<dim3(32, 4, 2), 256, 0, stream>>>(
        q_bf, k_bf, Wq_bf, Wk_bf, qh_f32, qh_bf, kh_bf);

    attn_sums_kernel<<<dim3(16, 128), 256, 0, stream>>>(qh_bf, kh_bf, mask, rinv);

    attn_write_kernel<<<dim3(16, 128), 256, 0, stream>>>(qh_bf, kh_bf, mask, rinv, attn);
}

// Round 4
// 415.028 us; speedup vs baseline: 1.0078x; 1.0078x over previous
//
#include <hip/hip_runtime.h>
#include <hip/hip_bf16.h>

// Problem: B=2, L=2048, NH=8, DH=64, DM=512, TEMP=8.
// Outputs (concat fp32): qh (2,8,2048,64) then attn (2,8,2048,2048).
//
// R4 structure: proj GEMM (fused f32->bf16 pack) -> single fused attn kernel.
// attn: 64 q-rows/block (grid 16x32). Each wave owns 16 rows, sweeps all 2048
// keys. Pass 1: row exp-sums (xor-shuffle over 16 col-lanes = full row sum,
// no cross-wave reduction, NO barriers). Pass 2: recompute scores, normalize,
// stage per-wave 16x256 bf16 tiles in LDS, flush as coalesced 1KB stores.
// K L2 traffic: 2 sweeps x 512 blocks... = 2 x 128 MB (4x less than R2).

typedef __attribute__((ext_vector_type(8))) short bf16x8_t;   // MFMA A/B frag
typedef __attribute__((ext_vector_type(4))) float f32x4_t;    // MFMA C/D frag
typedef __attribute__((ext_vector_type(4))) short s16x4_t;

#define MFMA16(a, b, c) __builtin_amdgcn_mfma_f32_16x16x32_bf16((a), (b), (c), 0, 0, 0)

// exp(x/8) == exp2(x * 0.125 * log2(e))
#define EXP2_SCALE 0.18033688f

__device__ __forceinline__ short f2bf(float x) {
    union { float f; unsigned u; } v; v.f = x;
    unsigned r = v.u + 0x7fffu + ((v.u >> 16) & 1u);
    return (short)(r >> 16);
}
__device__ __forceinline__ float bf2f(short x) {
    union { float f; unsigned u; } v;
    v.u = ((unsigned)(unsigned short)x) << 16;
    return v.f;
}
__device__ __forceinline__ bf16x8_t pack8(const float* p) {
    f32x4_t lo = *(const f32x4_t*)p;
    f32x4_t hi = *(const f32x4_t*)(p + 4);
    bf16x8_t r;
    r[0] = f2bf(lo[0]); r[1] = f2bf(lo[1]); r[2] = f2bf(lo[2]); r[3] = f2bf(lo[3]);
    r[4] = f2bf(hi[0]); r[5] = f2bf(hi[1]); r[6] = f2bf(hi[2]); r[7] = f2bf(hi[3]);
    return r;
}

// ---------------------------------------------------------------------------
// Kernel 1: C = A @ W^T, A in {q,k} (4096x512 f32), W in {W_q,W_k} (512x512).
// grid (32,4,2); inline f32->bf16 pack (proj is ~5us; convert-kernel split
// measured WORSE in R3 due to extra launch + HBM round-trip).
// ---------------------------------------------------------------------------
__global__ __launch_bounds__(256) void proj_kernel(
    const float* __restrict__ q, const float* __restrict__ k,
    const float* __restrict__ Wq, const float* __restrict__ Wk,
    float* __restrict__ qh_f32, short* __restrict__ qh_bf,
    short* __restrict__ kh_bf)
{
    const int z  = blockIdx.z;
    const float* A = z ? k  : q;
    const float* W = z ? Wk : Wq;
    const int m0 = blockIdx.x * 128;
    const int n0 = blockIdx.y * 128;
    const int tid  = threadIdx.x;
    const int wave = tid >> 6;
    const int lane = tid & 63;
    const int wm = (wave >> 1) * 64;
    const int wn = (wave & 1) * 64;
    const int lrow = lane & 15;
    const int lk   = (lane >> 4) * 8;

    f32x4_t acc[4][4] = {};

    for (int ks = 0; ks < 512; ks += 32) {
        bf16x8_t af[4], bfr[4];
#pragma unroll
        for (int mt = 0; mt < 4; ++mt)
            af[mt] = pack8(A + (size_t)(m0 + wm + mt * 16 + lrow) * 512 + ks + lk);
#pragma unroll
        for (int nt = 0; nt < 4; ++nt)
            bfr[nt] = pack8(W + (size_t)(n0 + wn + nt * 16 + lrow) * 512 + ks + lk);
#pragma unroll
        for (int mt = 0; mt < 4; ++mt)
#pragma unroll
            for (int nt = 0; nt < 4; ++nt)
                acc[mt][nt] = MFMA16(af[mt], bfr[nt], acc[mt][nt]);
    }

    const int g4 = (lane >> 4) * 4;
#pragma unroll
    for (int mt = 0; mt < 4; ++mt) {
#pragma unroll
        for (int r = 0; r < 4; ++r) {
            const int m  = m0 + wm + mt * 16 + g4 + r;
            const int bb = m >> 11;
            const int l  = m & 2047;
#pragma unroll
            for (int nt = 0; nt < 4; ++nt) {
                const int n = n0 + wn + nt * 16 + lrow;
                const int h = n >> 6;
                const int d = n & 63;
                const size_t idx = ((size_t)(bb * 8 + h) * 2048 + l) * 64 + d;
                const float v = acc[mt][nt][r];
                if (z == 0) {
                    qh_f32[idx] = v;
                    qh_bf[idx]  = f2bf(v);
                } else {
                    kh_bf[idx]  = f2bf(v);
                }
            }
        }
    }
}

// ---------------------------------------------------------------------------
// Kernel 2: fused attn softmax. grid (16,32): x=b*8+h, y=64-row q tile.
// 256 threads = 4 waves; wave w owns rows [q0+16w, q0+16w+16), all 2048 keys.
// No __syncthreads anywhere. LDS 33.8 KB -> 4 blocks/CU.
// ---------------------------------------------------------------------------
__global__ __launch_bounds__(256) void attn_kernel(
    const short* __restrict__ qh, const short* __restrict__ kh,
    const int* __restrict__ mask, float* __restrict__ attn)
{
    const int bh = blockIdx.x;          // 0..15
    const int b  = bh >> 3;
    const int q0 = blockIdx.y * 64;
    const int tid  = threadIdx.x;
    const int wave = tid >> 6;
    const int lane = tid & 63;
    const int lrow = lane & 15;         // key (col) index within 16
    const int lk   = (lane >> 4) * 8;   // K-dim offset (8 bf16)
    const int g4   = (lane >> 4) * 4;   // row-group base

    __shared__ short stage[4 * 16 * 264];
    short* st = stage + wave * (16 * 264);

    const short* Qb = qh + (size_t)bh * 2048 * 64;
    const short* Kb = kh + (size_t)bh * 2048 * 64;
    const int*   Mb = mask + b * 2048;

    const int qrow = q0 + wave * 16 + lrow;
    const bf16x8_t qf0 = *(const bf16x8_t*)(Qb + (size_t)qrow * 64 + lk);
    const bf16x8_t qf1 = *(const bf16x8_t*)(Qb + (size_t)qrow * 64 + lk + 32);

    // ---- pass 1: row exp-sums over all 2048 keys ----
    float sum[4] = {0.f, 0.f, 0.f, 0.f};
#pragma unroll 4
    for (int kc = 0; kc < 2048; kc += 16) {
        const short* kp = Kb + (size_t)(kc + lrow) * 64 + lk;
        const bf16x8_t b0 = *(const bf16x8_t*)kp;
        const bf16x8_t b1 = *(const bf16x8_t*)(kp + 32);
        const float bias2 = Mb[kc + lrow] ? 0.f : -1.0e9f;
        f32x4_t acc = {};
        acc = MFMA16(qf0, b0, acc);
        acc = MFMA16(qf1, b1, acc);
#pragma unroll
        for (int r = 0; r < 4; ++r)
            sum[r] += __builtin_amdgcn_exp2f(acc[r] * EXP2_SCALE + bias2);
    }
    // full row sums via xor-shuffle across the 16 column lanes
#pragma unroll
    for (int m = 1; m < 16; m <<= 1)
#pragma unroll
        for (int r = 0; r < 4; ++r)
            sum[r] += __shfl_xor(sum[r], m, 64);
    float rv[4];
#pragma unroll
    for (int r = 0; r < 4; ++r) rv[r] = 1.f / sum[r];

    // ---- pass 2: recompute, normalize, stage per-wave, coalesced flush ----
    float* outw = attn + ((size_t)bh * 2048 + q0 + wave * 16) * 2048;
#pragma unroll 1
    for (int t = 0; t < 8; ++t) {
        const int kbase = t * 256;
#pragma unroll 4
        for (int kl = 0; kl < 256; kl += 16) {
            const int kc = kbase + kl;
            const short* kp = Kb + (size_t)(kc + lrow) * 64 + lk;
            const bf16x8_t b0 = *(const bf16x8_t*)kp;
            const bf16x8_t b1 = *(const bf16x8_t*)(kp + 32);
            const float bias2 = Mb[kc + lrow] ? 0.f : -1.0e9f;
            f32x4_t acc = {};
            acc = MFMA16(qf0, b0, acc);
            acc = MFMA16(qf1, b1, acc);
#pragma unroll
            for (int r = 0; r < 4; ++r) {
                const float e =
                    __builtin_amdgcn_exp2f(acc[r] * EXP2_SCALE + bias2) * rv[r];
                st[(g4 + r) * 264 + kl + lrow] = f2bf(e);
            }
        }
        // flush: 16 rows x 1KB contiguous stores (64 lanes x 16B).
        // Same-wave LDS producer/consumer: compiler lgkmcnt waits suffice.
#pragma unroll
        for (int row = 0; row < 16; ++row) {
            const s16x4_t v = *(const s16x4_t*)(st + row * 264 + lane * 4);
            f32x4_t o;
            o[0] = bf2f(v[0]); o[1] = bf2f(v[1]);
            o[2] = bf2f(v[2]); o[3] = bf2f(v[3]);
            *(f32x4_t*)(outw + (size_t)row * 2048 + kbase + lane * 4) = o;
        }
    }
}

// ---------------------------------------------------------------------------
extern "C" void kernel_launch(void* const* d_in, const int* in_sizes, int n_in,
                              void* d_out, int out_size, void* d_ws, size_t ws_size,
                              hipStream_t stream)
{
    const float* q    = (const float*)d_in[0];
    const float* k    = (const float*)d_in[1];
    const int*   mask = (const int*)  d_in[3];
    const float* Wq   = (const float*)d_in[4];
    const float* Wk   = (const float*)d_in[5];

    float* out    = (float*)d_out;
    float* qh_f32 = out;                 // 2,097,152 floats
    float* attn   = out + 2097152;       // 67,108,864 floats

    short* qh_bf = (short*)d_ws;         // 4 MB
    short* kh_bf = qh_bf + 2097152;      // 4 MB

    proj_kernel<<<dim3(32, 4, 2), 256, 0, stream>>>(q, k, Wq, Wk, qh_f32, qh_bf, kh_bf);
    attn_kernel<<<dim3(16, 32), 256, 0, stream>>>(qh_bf, kh_bf, mask, attn);
}